// Round 22
// baseline (674.698 us; speedup 1.0000x reference)
//
#include <hip/hip_runtime.h>
#include <hip/hip_bf16.h>
#include <hip/hip_fp16.h>

#define NN 262144
#define EE 4194304
#define NG 16
#define NPER 16384
#define KK 7
#define TPAD 20
#define SLOT 18432

typedef unsigned long long u64;

__device__ __forceinline__ float wred(float v) {
    #pragma unroll
    for (int o = 32; o > 0; o >>= 1) v += __shfl_xor(v, o);
    return v;
}

__device__ __forceinline__ unsigned short f2h(float f) {
    return __half_as_ushort(__float2half_rn(f));
}
__device__ __forceinline__ float h2f(unsigned short s) {
    return __half2float(__ushort_as_half(s));
}

// ---------- fused init: gcur + normalized p vectors ----------
__global__ void prep_init(const float* __restrict__ p0, const float* __restrict__ p1,
                          float* __restrict__ pn, int* __restrict__ gcur) {
    int t = threadIdx.x; // 256 threads
    gcur[t] = t * SLOT;
    if (t < 64) {
        float v0 = (t < 32) ? p0[t] : 0.f;
        float s0 = wred(v0 * v0);
        if (t < 32) pn[t] = v0 * rsqrtf(s0);
        float v1 = p1[t];
        float s1 = wred(v1 * v1);
        pn[32 + t] = v1 * rsqrtf(s1);
    }
}

// ---------- pass A: LDS radix partition into 256 fixed-slot buckets (dst>>10) ----------
__global__ __launch_bounds__(256) void binA(const int* __restrict__ ei,
                                            const float* __restrict__ ew,
                                            int* __restrict__ gcur,
                                            uint2* __restrict__ bb) {
    __shared__ int hist[256], hofs[256], hcur[256], gpos[256], sd[256];
    __shared__ uint2 stage[4096];
    int t = threadIdx.x;
    int base = blockIdx.x * 4096;
    hist[t] = 0;
    __syncthreads();
    int dv[16];
    #pragma unroll
    for (int j = 0; j < 16; j++) {
        dv[j] = ei[EE + base + j * 256 + t];
        atomicAdd(&hist[dv[j] >> 10], 1);
    }
    __syncthreads();
    int cnt = hist[t];
    sd[t] = cnt;
    __syncthreads();
    #pragma unroll
    for (int off = 1; off < 256; off <<= 1) {
        int add = (t >= off) ? sd[t - off] : 0;
        __syncthreads();
        sd[t] += add;
        __syncthreads();
    }
    hofs[t] = sd[t] - cnt;
    hcur[t] = sd[t] - cnt;
    gpos[t] = atomicAdd(&gcur[t], cnt);
    __syncthreads();
    #pragma unroll
    for (int j = 0; j < 16; j++) {
        int e = base + j * 256 + t;
        int d = dv[j];
        int s = ei[e];
        unsigned wq = (unsigned)__float2uint_rn(ew[e] * 16383.f);
        unsigned payload = ((unsigned)s << 14) | wq;
        int p = atomicAdd(&hcur[d >> 10], 1);
        stage[p] = make_uint2((unsigned)d, payload);
    }
    __syncthreads();
    #pragma unroll
    for (int j = 0; j < 16; j++) {
        int k = j * 256 + t;
        uint2 en = stage[k];
        int b = (int)(en.x >> 10);
        bb[gpos[b] + (k - hofs[b])] = en;
    }
}

// ---------- per-bucket count + degree + local rowptr (LDS only, deterministic) ----------
__global__ __launch_bounds__(1024) void count_bucket(const uint2* __restrict__ bb,
                                                     const int* __restrict__ gcur,
                                                     int* __restrict__ rowptr,
                                                     int* __restrict__ btot,
                                                     float* __restrict__ rsqd,
                                                     float* __restrict__ invdeg) {
    __shared__ int cnt[1024];
    __shared__ int wsi[1024];
    __shared__ int sd[1024];
    int b = blockIdx.x, t = threadIdx.x;
    cnt[t] = 0;
    wsi[t] = 0;
    __syncthreads();
    int e0 = b * SLOT, e1 = gcur[b];
    for (int k = e0 + t; k < e1; k += 1024) {
        u64 raw = __builtin_nontemporal_load((const u64*)(bb + k));
        unsigned lo = (unsigned)raw;          // en.x (dst)
        unsigned hi = (unsigned)(raw >> 32);  // en.y (payload)
        int dl = (int)(lo & 1023u);
        atomicAdd(&cnt[dl], 1);
        atomicAdd(&wsi[dl], (int)(hi & 16383u));
    }
    __syncthreads();
    int node = (b << 10) + t;
    float deg = 1.f + (float)wsi[t] * (1.f / 16383.f);
    rsqd[node] = rsqrtf(deg);
    invdeg[node] = 1.f / deg;
    int v = cnt[t];
    sd[t] = v;
    __syncthreads();
    #pragma unroll
    for (int off = 1; off < 1024; off <<= 1) {
        int add = (t >= off) ? sd[t - off] : 0;
        __syncthreads();
        sd[t] += add;
        __syncthreads();
    }
    rowptr[node] = sd[t] - v;
    if (t == 1023) btot[b] = sd[1023];
}

__global__ void scan256(const int* __restrict__ btot, int* __restrict__ bbase) {
    __shared__ int sd[256];
    int t = threadIdx.x;
    int v = btot[t];
    sd[t] = v;
    __syncthreads();
    #pragma unroll
    for (int off = 1; off < 256; off <<= 1) {
        int add = (t >= off) ? sd[t - off] : 0;
        __syncthreads();
        sd[t] += add;
        __syncthreads();
    }
    bbase[t] = sd[t] - v;
}

__global__ void finalize_rowptr(int* __restrict__ rowptr, const int* __restrict__ bbase) {
    int i = blockIdx.x * 256 + threadIdx.x;
    rowptr[i] += bbase[i >> 10];
    if (i == 0) rowptr[NN] = EE;
}

// ---------- pass B: per-bucket fine scatter, LDS cursors; applies rsqd[src] ----------
__global__ __launch_bounds__(1024) void binB(const int* __restrict__ rowptr,
                                             const int* __restrict__ gcur,
                                             const uint2* __restrict__ bb,
                                             const float* __restrict__ rsqd,
                                             unsigned* __restrict__ evw) {
    __shared__ int lcur[1024];
    int b = blockIdx.x, t = threadIdx.x;
    lcur[t] = rowptr[(b << 10) + t];
    __syncthreads();
    int e0 = b * SLOT, e1 = gcur[b];
    for (int k = e0 + t; k < e1; k += 1024) {
        u64 raw = __builtin_nontemporal_load((const u64*)(bb + k));
        unsigned lo = (unsigned)raw;
        unsigned hi = (unsigned)(raw >> 32);
        int dl = (int)(lo & 1023u);
        unsigned s = hi >> 14;
        float wt = (float)(hi & 16383u) * (1.f / 16383.f) * rsqd[s];
        int pos = atomicAdd(&lcur[dl], 1);
        evw[pos] = (s << 14) | (unsigned)__float2uint_rn(wt * 16383.f);
    }
}

// ---------- fused: layer-0 scores + f16 conversion + per-chunk top-7 ----------
// block = g*16+c covers nodes [blockIdx*1024, +1024); emits cand directly (no scores pass)
__global__ __launch_bounds__(256) void scores0_topk1(
    const float* __restrict__ x, const float* __restrict__ pn0,
    unsigned short* __restrict__ xh, float2* __restrict__ cand) {
    __shared__ float p[32];
    if (threadIdx.x < 32) p[threadIdx.x] = pn0[threadIdx.x];
    __syncthreads();
    int t = threadIdx.x;
    float lv[KK];
    int li[KK];
    #pragma unroll
    for (int j = 0; j < KK; j++) { lv[j] = -INFINITY; li[j] = 0; }
    #pragma unroll
    for (int it = 0; it < 4; ++it) {
        int idx = it * 256 + t;
        int n = blockIdx.x * 1024 + idx;
        const float4* xr = (const float4*)(x + (size_t)n * 32);
        float s = 0.f;
        unsigned wv[16];
        #pragma unroll
        for (int j = 0; j < 8; j++) {
            float4 v = xr[j];
            s += v.x * p[j * 4] + v.y * p[j * 4 + 1] + v.z * p[j * 4 + 2] + v.w * p[j * 4 + 3];
            wv[2 * j]     = (unsigned)f2h(v.x) | ((unsigned)f2h(v.y) << 16);
            wv[2 * j + 1] = (unsigned)f2h(v.z) | ((unsigned)f2h(v.w) << 16);
        }
        uint4* xo = (uint4*)(xh + (size_t)n * 32);
        xo[0] = make_uint4(wv[0], wv[1], wv[2], wv[3]);
        xo[1] = make_uint4(wv[4], wv[5], wv[6], wv[7]);
        xo[2] = make_uint4(wv[8], wv[9], wv[10], wv[11]);
        xo[3] = make_uint4(wv[12], wv[13], wv[14], wv[15]);
        if (s > lv[KK - 1]) {
            int j = KK - 1;
            while (j > 0 && lv[j - 1] < s) { lv[j] = lv[j - 1]; li[j] = li[j - 1]; j--; }
            lv[j] = s; li[j] = idx;
        }
    }
    __shared__ float sval[256];
    __shared__ int sidx[256];
    __shared__ int swin;
    int cons = 0;
    for (int r = 0; r < KK; r++) {
        sval[t] = (cons < KK) ? lv[cons] : -INFINITY;
        sidx[t] = t;
        __syncthreads();
        for (int s = 128; s > 0; s >>= 1) {
            if (t < s) {
                if (sval[t + s] > sval[t]) { sval[t] = sval[t + s]; sidx[t] = sidx[t + s]; }
            }
            __syncthreads();
        }
        if (t == 0) swin = sidx[0];
        __syncthreads();
        if (t == swin) {
            cand[blockIdx.x * KK + r] =
                make_float2(lv[cons], __int_as_float(blockIdx.x * 1024 + li[cons]));
            cons++;
        }
        __syncthreads();
    }
}

// ---------- topk1 (layer 1, reads scores written by post0) ----------
__global__ void topk1(const float* __restrict__ scores, float2* __restrict__ cand) {
    int t = threadIdx.x;
    float lv[KK];
    int li[KK];
    #pragma unroll
    for (int j = 0; j < KK; j++) { lv[j] = -INFINITY; li[j] = 0; }
    const float* sg = scores + (size_t)blockIdx.x * 1024;
    #pragma unroll
    for (int it = 0; it < 4; ++it) {
        int idx = it * 256 + t;
        float v = sg[idx];
        if (v > lv[KK - 1]) {
            int j = KK - 1;
            while (j > 0 && lv[j - 1] < v) { lv[j] = lv[j - 1]; li[j] = li[j - 1]; j--; }
            lv[j] = v; li[j] = idx;
        }
    }
    __shared__ float sval[256];
    __shared__ int sidx[256];
    __shared__ int swin;
    int cons = 0;
    for (int r = 0; r < KK; r++) {
        sval[t] = (cons < KK) ? lv[cons] : -INFINITY;
        sidx[t] = t;
        __syncthreads();
        for (int s = 128; s > 0; s >>= 1) {
            if (t < s) {
                if (sval[t + s] > sval[t]) { sval[t] = sval[t + s]; sidx[t] = sidx[t + s]; }
            }
            __syncthreads();
        }
        if (t == 0) swin = sidx[0];
        __syncthreads();
        if (t == swin) {
            cand[blockIdx.x * KK + r] =
                make_float2(lv[cons], __int_as_float(blockIdx.x * 1024 + li[cons]));
            cons++;
        }
        __syncthreads();
    }
}

// ---------- fused topk2 + Z (f32 source, layer 0) ----------
__global__ void topk2z(const float2* __restrict__ cand, const float* __restrict__ h,
                       int din, float* __restrict__ Z) {
    int g = blockIdx.x, t = threadIdx.x; // 128 threads
    __shared__ float tv[KK];
    __shared__ int ti[KK];
    float v = -INFINITY;
    int id = 0;
    if (t < 16 * KK) {
        float2 cv = cand[g * 16 * KK + t];
        v = cv.x;
        id = __float_as_int(cv.y);
    }
    __shared__ float sval[128];
    __shared__ int sidx[128];
    __shared__ int swin;
    for (int r = 0; r < KK; r++) {
        sval[t] = v;
        sidx[t] = t;
        __syncthreads();
        for (int s = 64; s > 0; s >>= 1) {
            if (t < s) {
                if (sval[t + s] > sval[t]) { sval[t] = sval[t + s]; sidx[t] = sidx[t + s]; }
            }
            __syncthreads();
        }
        if (t == 0) swin = sidx[0];
        __syncthreads();
        if (t == swin) {
            tv[r] = v;
            ti[r] = id;
            v = -INFINITY;
        }
        __syncthreads();
    }
    if (t < din) {
        float acc = 0.f;
        #pragma unroll
        for (int j = 0; j < KK; j++) {
            acc += tanhf(tv[j]) * h[(size_t)ti[j] * din + t];
        }
        Z[g * din + t] = acc * (1.f / 7.f);
    }
}

// ---------- fused topk2 + Z (f16 source, layer 1) ----------
__global__ void topk2z_h(const float2* __restrict__ cand, const unsigned short* __restrict__ h,
                         int din, float* __restrict__ Z) {
    int g = blockIdx.x, t = threadIdx.x; // 128 threads
    __shared__ float tv[KK];
    __shared__ int ti[KK];
    float v = -INFINITY;
    int id = 0;
    if (t < 16 * KK) {
        float2 cv = cand[g * 16 * KK + t];
        v = cv.x;
        id = __float_as_int(cv.y);
    }
    __shared__ float sval[128];
    __shared__ int sidx[128];
    __shared__ int swin;
    for (int r = 0; r < KK; r++) {
        sval[t] = v;
        sidx[t] = t;
        __syncthreads();
        for (int s = 64; s > 0; s >>= 1) {
            if (t < s) {
                if (sval[t + s] > sval[t]) { sval[t] = sval[t + s]; sidx[t] = sidx[t + s]; }
            }
            __syncthreads();
        }
        if (t == 0) swin = sidx[0];
        __syncthreads();
        if (t == swin) {
            tv[r] = v;
            ti[r] = id;
            v = -INFINITY;
        }
        __syncthreads();
    }
    if (t < din) {
        float acc = 0.f;
        #pragma unroll
        for (int j = 0; j < KK; j++) {
            acc += tanhf(tv[j]) * h2f(h[(size_t)ti[j] * din + t]);
        }
        Z[g * din + t] = acc * (1.f / 7.f);
    }
}

// ---------- GRU: per-slice partial matvec, 4 rows per 16-lane group ----------
__global__ void gru_matvec(const float* __restrict__ Whh, const float* __restrict__ gh,
                           float* __restrict__ ghl, int P) {
    int t = threadIdx.x;
    int g = t >> 4, l16 = t & 15;
    int row0 = blockIdx.x * 64 + g * 4;
    int k0 = blockIdx.y * 512;
    float acc[4][16];
    #pragma unroll
    for (int r = 0; r < 4; r++)
        #pragma unroll
        for (int b = 0; b < 16; b++) acc[r][b] = 0.f;
    const float* wr = Whh + (size_t)row0 * P + k0 + l16 * 4;
    const float* gr = gh + k0 + l16 * 4;
    for (int kk = 0; kk < 8; ++kk) {
        float4 a0 = *(const float4*)(wr + kk * 64);
        float4 a1 = *(const float4*)(wr + (size_t)P + kk * 64);
        float4 a2 = *(const float4*)(wr + (size_t)2 * P + kk * 64);
        float4 a3 = *(const float4*)(wr + (size_t)3 * P + kk * 64);
        #pragma unroll
        for (int b = 0; b < 16; b++) {
            float4 gv = *(const float4*)(gr + (size_t)b * P + kk * 64);
            acc[0][b] += a0.x * gv.x + a0.y * gv.y + a0.z * gv.z + a0.w * gv.w;
            acc[1][b] += a1.x * gv.x + a1.y * gv.y + a1.z * gv.z + a1.w * gv.w;
            acc[2][b] += a2.x * gv.x + a2.y * gv.y + a2.z * gv.z + a2.w * gv.w;
            acc[3][b] += a3.x * gv.x + a3.y * gv.y + a3.z * gv.z + a3.w * gv.w;
        }
    }
    size_t sstr = (size_t)gridDim.x * 1024; // rows*16
    #pragma unroll
    for (int r = 0; r < 4; r++) {
        #pragma unroll
        for (int b = 0; b < 16; b++) {
            float v = acc[r][b];
            v += __shfl_xor(v, 1); v += __shfl_xor(v, 2);
            v += __shfl_xor(v, 4); v += __shfl_xor(v, 8);
            if (l16 == b) ghl[(size_t)blockIdx.y * sstr + (size_t)(row0 + r) * 16 + b] = v;
        }
    }
}

// ---------- GRU gates, batch-split: block (pb, b) computes gv[b][p] ----------
__global__ __launch_bounds__(256) void gate_kernel(
    const float* __restrict__ Wih, const float* __restrict__ bih,
    const float* __restrict__ bhh, const float* __restrict__ gh,
    const float* __restrict__ ghl, const float* __restrict__ Zg,
    float* __restrict__ gvt, int P, int din, int NS) {
    __shared__ float Zs[64];
    int t = threadIdx.x;
    int b = blockIdx.y;
    if (t < din) Zs[t] = Zg[b * din + t];
    __syncthreads();
    int p = blockIdx.x * 256 + t;
    float ir = bih[p], iz = bih[P + p], inn = bih[2 * P + p];
    const float* w_r = Wih + (size_t)p * din;
    const float* w_z = Wih + (size_t)(P + p) * din;
    const float* w_n = Wih + (size_t)(2 * P + p) * din;
    for (int d = 0; d < din; d += 4) {
        float4 zr = *(const float4*)(Zs + d);
        float4 a = *(const float4*)(w_r + d);
        float4 bq = *(const float4*)(w_z + d);
        float4 c = *(const float4*)(w_n + d);
        ir += a.x * zr.x + a.y * zr.y + a.z * zr.z + a.w * zr.w;
        iz += bq.x * zr.x + bq.y * zr.y + bq.z * zr.z + bq.w * zr.w;
        inn += c.x * zr.x + c.y * zr.y + c.z * zr.z + c.w * zr.w;
    }
    float hr = bhh[p], hz = bhh[P + p], hn = bhh[2 * P + p];
    size_t sstr = (size_t)48 * P;
    for (int s2 = 0; s2 < NS; s2++) {
        const float* g2 = ghl + (size_t)s2 * sstr;
        hr += g2[(size_t)p * 16 + b];
        hz += g2[(size_t)(P + p) * 16 + b];
        hn += g2[(size_t)(2 * P + p) * 16 + b];
    }
    float r = 1.f / (1.f + expf(-(ir + hr)));
    float z = 1.f / (1.f + expf(-(iz + hz)));
    float n = tanhf(inn + r * hn);
    float hprev = gh[(size_t)b * P + p];
    gvt[(size_t)b * P + p] = (1.f - z) * n + z * hprev;
}

// Wev[p] = mean over 16 batches
__global__ void gate_reduce(const float* __restrict__ gvt, float* __restrict__ Wev, int P) {
    int p = blockIdx.x * 256 + threadIdx.x;
    float s = 0.f;
    #pragma unroll
    for (int b = 0; b < 16; b++) s += gvt[(size_t)b * P + p];
    Wev[p] = s * (1.f / 16.f);
}

// ---------- edge aggregation: 4 dims/lane (uint2 gather), f16 output ----------
template<int DIN, int LSHL>
__global__ void agg_kernel(const unsigned short* __restrict__ hin,
                           const int* __restrict__ rowptr, const unsigned* __restrict__ evw,
                           const float* __restrict__ rsqd, const float* __restrict__ invdeg,
                           unsigned short* __restrict__ aggh, float* __restrict__ cc) {
    int t = threadIdx.x;
    int lane = t & ((1 << LSHL) - 1);
    int i = blockIdx.x * (256 >> LSHL) + (t >> LSHL);
    int e0 = rowptr[i], e1 = rowptr[i + 1];
    float a0 = 0.f, a1 = 0.f, a2 = 0.f, a3 = 0.f;
    int csi = 0;
    for (int e = e0; e < e1; e += 8) {
        unsigned ev[8];
        #pragma unroll
        for (int j = 0; j < 8; j++) {
            ev[j] = (e + j < e1) ? evw[e + j] : ((unsigned)i << 14);
        }
        uint2 hv[8];
        #pragma unroll
        for (int j = 0; j < 8; j++) {
            hv[j] = *(const uint2*)(hin + (size_t)(ev[j] >> 14) * DIN + 4 * lane);
        }
        #pragma unroll
        for (int j = 0; j < 8; j++) {
            int wq = (int)(ev[j] & 16383u);
            csi += wq;
            float nw = (float)wq;
            a0 += nw * h2f((unsigned short)(hv[j].x & 0xffffu));
            a1 += nw * h2f((unsigned short)(hv[j].x >> 16));
            a2 += nw * h2f((unsigned short)(hv[j].y & 0xffffu));
            a3 += nw * h2f((unsigned short)(hv[j].y >> 16));
        }
    }
    float rsi = rsqd[i] * (1.f / 16383.f);
    float idg = invdeg[i];
    uint2 hs = *(const uint2*)(hin + (size_t)i * DIN + 4 * lane);
    float r0 = a0 * rsi + h2f((unsigned short)(hs.x & 0xffffu)) * idg;
    float r1 = a1 * rsi + h2f((unsigned short)(hs.x >> 16)) * idg;
    float r2 = a2 * rsi + h2f((unsigned short)(hs.y & 0xffffu)) * idg;
    float r3 = a3 * rsi + h2f((unsigned short)(hs.y >> 16)) * idg;
    uint2 ro;
    ro.x = (unsigned)f2h(r0) | ((unsigned)f2h(r1) << 16);
    ro.y = (unsigned)f2h(r2) | ((unsigned)f2h(r3) << 16);
    *(uint2*)(aggh + (size_t)i * DIN + 4 * lane) = ro;
    #pragma unroll
    for (int o = (1 << LSHL) >> 1; o > 0; o >>= 1) csi += __shfl_xor(csi, o);
    if (lane == 0) cc[i] = (float)csi * rsi + idg;
}

// ---------- post kernels: 4 waves/block, LDS-staged A tiles (f16 agg input) ----------
__global__ __launch_bounds__(256) void post0_kernel(
    const unsigned short* __restrict__ aggh, const float* __restrict__ cc,
    const float* __restrict__ Wev, const float* __restrict__ gcnb,
    const float* __restrict__ lng, const float* __restrict__ lnb,
    const float* __restrict__ pn1, unsigned short* __restrict__ h1h,
    float* __restrict__ scores) {
    __shared__ float stage[4][512];
    __shared__ float tile[4][64 * TPAD];
    const int wv = threadIdx.x >> 6;
    const int lane = threadIdx.x & 63;
    const int tb = blockIdx.x * 256 + wv * 64;
    const int j = lane & 15, q = lane >> 4;
    float gL = gcnb[lane];
    float lgv[16], lbv[16], pnv[16];
    #pragma unroll
    for (int r = 0; r < 16; r++) {
        lgv[r] = lng[q * 16 + r];
        lbv[r] = lnb[q * 16 + r];
        pnv[r] = pn1[q * 16 + r];
    }
    float* st = stage[wv];
    float* trow = tile[wv] + lane * TPAD;
    auto do_chunk = [&](int C) {
        __syncthreads();
        {
            const uint2* src = (const uint2*)(aggh + (size_t)(tb + C * 16) * 32);
            #pragma unroll
            for (int it = 0; it < 2; ++it) {
                uint2 hp = src[it * 64 + lane];
                float4 f;
                f.x = h2f((unsigned short)(hp.x & 0xffffu));
                f.y = h2f((unsigned short)(hp.x >> 16));
                f.z = h2f((unsigned short)(hp.y & 0xffffu));
                f.w = h2f((unsigned short)(hp.y >> 16));
                *(float4*)(st + (it * 64 + lane) * 4) = f;
            }
        }
        __syncthreads();
        float v[16];
        #pragma unroll
        for (int k = 0; k < 16; k++) v[k] = 0.f;
        for (int db = 0; db < 8; ++db) {
            float wc0 = Wev[(db * 4 + 0) * 64 + lane];
            float wc1 = Wev[(db * 4 + 1) * 64 + lane];
            float wc2 = Wev[(db * 4 + 2) * 64 + lane];
            float wc3 = Wev[(db * 4 + 3) * 64 + lane];
            #pragma unroll
            for (int k = 0; k < 16; k++) {
                float4 a = *(const float4*)(st + k * 32 + db * 4);
                v[k] += a.x * wc0 + a.y * wc1 + a.z * wc2 + a.w * wc3;
            }
        }
        __syncthreads();
        #pragma unroll
        for (int k = 0; k < 16; k++) trow[k] = v[k] + gL * cc[tb + C * 16 + k];
        __syncthreads();
        float av[16];
        #pragma unroll
        for (int r = 0; r < 16; r++) av[r] = tile[wv][(q * 16 + r) * TPAD + j];
        float s1 = 0.f, s2 = 0.f;
        #pragma unroll
        for (int r = 0; r < 16; r++) { s1 += av[r]; s2 += av[r] * av[r]; }
        s1 += __shfl_xor(s1, 16); s1 += __shfl_xor(s1, 32);
        s2 += __shfl_xor(s2, 16); s2 += __shfl_xor(s2, 32);
        float mu = s1 * (1.f / 64.f);
        float rstd = rsqrtf(s2 * (1.f / 64.f) - mu * mu + 1e-5f);
        float hv[16];
        float sc = 0.f;
        #pragma unroll
        for (int r = 0; r < 16; r++) {
            hv[r] = fmaxf((av[r] - mu) * rstd * lgv[r] + lbv[r], 0.f);
            sc += hv[r] * pnv[r];
        }
        int node = tb + C * 16 + j;
        uint4 o0, o1;
        o0.x = (unsigned)f2h(hv[0])  | ((unsigned)f2h(hv[1])  << 16);
        o0.y = (unsigned)f2h(hv[2])  | ((unsigned)f2h(hv[3])  << 16);
        o0.z = (unsigned)f2h(hv[4])  | ((unsigned)f2h(hv[5])  << 16);
        o0.w = (unsigned)f2h(hv[6])  | ((unsigned)f2h(hv[7])  << 16);
        o1.x = (unsigned)f2h(hv[8])  | ((unsigned)f2h(hv[9])  << 16);
        o1.y = (unsigned)f2h(hv[10]) | ((unsigned)f2h(hv[11]) << 16);
        o1.z = (unsigned)f2h(hv[12]) | ((unsigned)f2h(hv[13]) << 16);
        o1.w = (unsigned)f2h(hv[14]) | ((unsigned)f2h(hv[15]) << 16);
        *(uint4*)(h1h + (size_t)node * 64 + q * 16) = o0;
        *(uint4*)(h1h + (size_t)node * 64 + q * 16 + 8) = o1;
        sc += __shfl_xor(sc, 16); sc += __shfl_xor(sc, 32);
        if (q == 0) scores[node] = sc;
    };
    do_chunk(0); do_chunk(1); do_chunk(2); do_chunk(3);
}

__global__ __launch_bounds__(256) void post1_kernel(
    const unsigned short* __restrict__ aggh, const float* __restrict__ cc,
    const float* __restrict__ Wev, const float* __restrict__ gcnb,
    const float* __restrict__ lng, const float* __restrict__ lnb,
    const float* __restrict__ Wp, const float* __restrict__ bp,
    float* __restrict__ out) {
    __shared__ float stage[4][1024];
    __shared__ float tile[4][64 * TPAD];
    const int wv = threadIdx.x >> 6;
    const int lane = threadIdx.x & 63;
    const int tb = blockIdx.x * 256 + wv * 64;
    const int j = lane & 15, q = lane >> 4;
    float gL = gcnb[lane];
    float lgv[16], lbv[16];
    #pragma unroll
    for (int r = 0; r < 16; r++) {
        lgv[r] = lng[q * 16 + r];
        lbv[r] = lnb[q * 16 + r];
    }
    float bpv[10];
    #pragma unroll
    for (int t2 = 0; t2 < 10; t2++) bpv[t2] = bp[t2];
    float* st = stage[wv];
    float* trow = tile[wv] + lane * TPAD;
    auto do_chunk = [&](int C) {
        __syncthreads();
        {
            const uint2* src = (const uint2*)(aggh + (size_t)(tb + C * 16) * 64);
            #pragma unroll
            for (int it = 0; it < 4; ++it) {
                uint2 hp = src[it * 64 + lane];
                float4 f;
                f.x = h2f((unsigned short)(hp.x & 0xffffu));
                f.y = h2f((unsigned short)(hp.x >> 16));
                f.z = h2f((unsigned short)(hp.y & 0xffffu));
                f.w = h2f((unsigned short)(hp.y >> 16));
                *(float4*)(st + (it * 64 + lane) * 4) = f;
            }
        }
        __syncthreads();
        float v[16];
        #pragma unroll
        for (int k = 0; k < 16; k++) v[k] = 0.f;
        for (int db = 0; db < 16; ++db) {
            float wc0 = Wev[(db * 4 + 0) * 64 + lane];
            float wc1 = Wev[(db * 4 + 1) * 64 + lane];
            float wc2 = Wev[(db * 4 + 2) * 64 + lane];
            float wc3 = Wev[(db * 4 + 3) * 64 + lane];
            #pragma unroll
            for (int k = 0; k < 16; k++) {
                float4 a = *(const float4*)(st + k * 64 + db * 4);
                v[k] += a.x * wc0 + a.y * wc1 + a.z * wc2 + a.w * wc3;
            }
        }
        __syncthreads();
        #pragma unroll
        for (int k = 0; k < 16; k++) trow[k] = v[k] + gL * cc[tb + C * 16 + k];
        __syncthreads();
        float av[16];
        #pragma unroll
        for (int r = 0; r < 16; r++) av[r] = tile[wv][(q * 16 + r) * TPAD + j];
        float s1 = 0.f, s2 = 0.f;
        #pragma unroll
        for (int r = 0; r < 16; r++) { s1 += av[r]; s2 += av[r] * av[r]; }
        s1 += __shfl_xor(s1, 16); s1 += __shfl_xor(s1, 32);
        s2 += __shfl_xor(s2, 16); s2 += __shfl_xor(s2, 32);
        float mu = s1 * (1.f / 64.f);
        float rstd = rsqrtf(s2 * (1.f / 64.f) - mu * mu + 1e-5f);
        float hv[16];
        #pragma unroll
        for (int r = 0; r < 16; r++)
            hv[r] = fmaxf((av[r] - mu) * rstd * lgv[r] + lbv[r], 0.f);
        float oa[10];
        #pragma unroll
        for (int t2 = 0; t2 < 10; t2++) oa[t2] = 0.f;
        #pragma unroll
        for (int r = 0; r < 16; r++) {
            const float* wpb = Wp + (size_t)(q * 16 + r) * 2;
            float2 w0 = *(const float2*)(wpb);
            float2 w1 = *(const float2*)(wpb + 128);
            float2 w2 = *(const float2*)(wpb + 256);
            float2 w3 = *(const float2*)(wpb + 384);
            float2 w4 = *(const float2*)(wpb + 512);
            oa[0] += hv[r] * w0.x; oa[1] += hv[r] * w0.y;
            oa[2] += hv[r] * w1.x; oa[3] += hv[r] * w1.y;
            oa[4] += hv[r] * w2.x; oa[5] += hv[r] * w2.y;
            oa[6] += hv[r] * w3.x; oa[7] += hv[r] * w3.y;
            oa[8] += hv[r] * w4.x; oa[9] += hv[r] * w4.y;
        }
        #pragma unroll
        for (int t2 = 0; t2 < 10; t2++) {
            oa[t2] += __shfl_xor(oa[t2], 16);
            oa[t2] += __shfl_xor(oa[t2], 32);
        }
        if (q == 0) {
            int node = tb + C * 16 + j;
            #pragma unroll
            for (int t2 = 0; t2 < 10; t2++) out[(size_t)node * 10 + t2] = oa[t2] + bpv[t2];
        }
    };
    do_chunk(0); do_chunk(1); do_chunk(2); do_chunk(3);
}

extern "C" void kernel_launch(void* const* d_in, const int* in_sizes, int n_in,
                              void* d_out, int out_size, void* d_ws, size_t ws_size,
                              hipStream_t stream) {
    const float* x     = (const float*)d_in[0];
    const int*   ei    = (const int*)d_in[1];
    const float* ew    = (const float*)d_in[2];
    const float* p0    = (const float*)d_in[5];
    const float* p1    = (const float*)d_in[6];
    const float* Wih0  = (const float*)d_in[7];
    const float* Whh0  = (const float*)d_in[8];
    const float* bih0  = (const float*)d_in[9];
    const float* bhh0  = (const float*)d_in[10];
    const float* Wih1  = (const float*)d_in[11];
    const float* Whh1  = (const float*)d_in[12];
    const float* bih1  = (const float*)d_in[13];
    const float* bhh1  = (const float*)d_in[14];
    const float* gruh0 = (const float*)d_in[15];
    const float* gruh1 = (const float*)d_in[16];
    const float* gcnb0 = (const float*)d_in[17];
    const float* gcnb1 = (const float*)d_in[18];
    const float* lng0  = (const float*)d_in[19];
    const float* lnb0  = (const float*)d_in[20];
    const float* lng1  = (const float*)d_in[21];
    const float* lnb1  = (const float*)d_in[22];
    const float* Wp    = (const float*)d_in[23];
    const float* bp    = (const float*)d_in[24];
    float* out = (float*)d_out;

    // workspace carve
    char* w = (char*)d_ws;
    size_t off = 0;
    auto alloc = [&](size_t bytes) -> void* {
        void* p = w + off;
        off += (bytes + 255) & ~(size_t)255;
        return p;
    };
    int*      rowptr = (int*)alloc((NN + 1) * sizeof(int));
    unsigned* evw    = (unsigned*)alloc((size_t)EE * sizeof(unsigned));
    float*    rsqd   = (float*)alloc(NN * sizeof(float));
    float*    invdeg = (float*)alloc(NN * sizeof(float));
    float*    scores = (float*)alloc(NN * sizeof(float));
    float2*   cand   = (float2*)alloc(NG * 16 * KK * sizeof(float2));
    float*    Z      = (float*)alloc(16 * 64 * sizeof(float));
    float*    ghl    = (float*)alloc((size_t)8 * 196608 * sizeof(float));
    float*    gvt    = (float*)alloc((size_t)16 * 4096 * sizeof(float));
    float*    Wev    = (float*)alloc(4096 * sizeof(float));
    float*    cc     = (float*)alloc(NN * sizeof(float));
    float*    agg    = (float*)alloc((size_t)NN * 64 * sizeof(float));
    unsigned short* xh  = (unsigned short*)alloc((size_t)NN * 32 * sizeof(unsigned short));
    unsigned short* h1h = (unsigned short*)alloc((size_t)NN * 64 * sizeof(unsigned short));
    float*    pn     = (float*)alloc(96 * sizeof(float));
    int*      gcur   = (int*)alloc(256 * sizeof(int));
    int*      btot   = (int*)alloc(256 * sizeof(int));
    int*      bbase  = (int*)alloc(256 * sizeof(int));

    // bb (256*SLOT*8B = 37.75MB) aliases into agg (67MB); aggh (f16) also in agg.
    uint2* bb = (uint2*)agg;
    unsigned short* aggh = (unsigned short*)agg;

    // --- CSR build: fixed-slot radix partition -> per-bucket count -> scatter ---
    prep_init<<<1, 256, 0, stream>>>(p0, p1, pn, gcur);
    binA<<<EE / 4096, 256, 0, stream>>>(ei, ew, gcur, bb);
    count_bucket<<<256, 1024, 0, stream>>>(bb, gcur, rowptr, btot, rsqd, invdeg);
    scan256<<<1, 256, 0, stream>>>(btot, bbase);
    finalize_rowptr<<<NN / 256, 256, 0, stream>>>(rowptr, bbase);
    binB<<<256, 1024, 0, stream>>>(rowptr, gcur, bb, rsqd, evw);

    // --- layer 0 ---
    scores0_topk1<<<NN / 1024, 256, 0, stream>>>(x, pn, xh, cand);
    topk2z<<<NG, 128, 0, stream>>>(cand, x, 32, Z);
    gru_matvec<<<dim3(6144 / 64, 4), 256, 0, stream>>>(Whh0, gruh0, ghl, 2048);
    gate_kernel<<<dim3(2048 / 256, 16), 256, 0, stream>>>(Wih0, bih0, bhh0, gruh0, ghl, Z, gvt, 2048, 32, 4);
    gate_reduce<<<2048 / 256, 256, 0, stream>>>(gvt, Wev, 2048);
    agg_kernel<32, 3><<<NN / 32, 256, 0, stream>>>(xh, rowptr, evw, rsqd, invdeg, aggh, cc);
    post0_kernel<<<NN / 256, 256, 0, stream>>>(aggh, cc, Wev, gcnb0, lng0, lnb0, pn + 32, h1h, scores);

    // --- layer 1 ---
    topk1<<<NN / 1024, 256, 0, stream>>>(scores, cand);
    topk2z_h<<<NG, 128, 0, stream>>>(cand, h1h, 64, Z);
    gru_matvec<<<dim3(12288 / 64, 8), 256, 0, stream>>>(Whh1, gruh1, ghl, 4096);
    gate_kernel<<<dim3(4096 / 256, 16), 256, 0, stream>>>(Wih1, bih1, bhh1, gruh1, ghl, Z, gvt, 4096, 64, 8);
    gate_reduce<<<4096 / 256, 256, 0, stream>>>(gvt, Wev, 4096);
    agg_kernel<64, 4><<<NN / 16, 256, 0, stream>>>(h1h, rowptr, evw, rsqd, invdeg, aggh, cc);
    post1_kernel<<<NN / 256, 256, 0, stream>>>(aggh, cc, Wev, gcnb1, lng1, lnb1, Wp, bp, out);
}

// Round 23
// 634.180 us; speedup vs baseline: 1.0639x; 1.0639x over previous
//
#include <hip/hip_runtime.h>
#include <hip/hip_bf16.h>
#include <hip/hip_fp16.h>

#define NN 262144
#define EE 4194304
#define NG 16
#define NPER 16384
#define KK 7
#define TPAD 20
#define SLOT 18432

typedef unsigned long long u64;

__device__ __forceinline__ float wred(float v) {
    #pragma unroll
    for (int o = 32; o > 0; o >>= 1) v += __shfl_xor(v, o);
    return v;
}

__device__ __forceinline__ unsigned short f2h(float f) {
    return __half_as_ushort(__float2half_rn(f));
}
__device__ __forceinline__ float h2f(unsigned short s) {
    return __half2float(__ushort_as_half(s));
}

// ---------- p normalization ----------
__global__ void prep_p(const float* __restrict__ p0, const float* __restrict__ p1,
                       float* __restrict__ pn) {
    int t = threadIdx.x;
    float v0 = (t < 32) ? p0[t] : 0.f;
    float s0 = wred(v0 * v0);
    if (t < 32) pn[t] = v0 * rsqrtf(s0);
    float v1 = p1[t];
    float s1 = wred(v1 * v1);
    pn[32 + t] = v1 * rsqrtf(s1);
}

__global__ void init_gcur(int* __restrict__ gcur) {
    gcur[threadIdx.x] = (int)threadIdx.x * SLOT;
}

// ---------- pass A: LDS radix partition into 256 fixed-slot buckets (dst>>10) ----------
__global__ __launch_bounds__(256) void binA(const int* __restrict__ ei,
                                            const float* __restrict__ ew,
                                            int* __restrict__ gcur,
                                            uint2* __restrict__ bb) {
    __shared__ int hist[256], hofs[256], hcur[256], gpos[256], sd[256];
    __shared__ uint2 stage[4096];
    int t = threadIdx.x;
    int base = blockIdx.x * 4096;
    hist[t] = 0;
    __syncthreads();
    int dv[16];
    #pragma unroll
    for (int j = 0; j < 16; j++) {
        dv[j] = ei[EE + base + j * 256 + t];
        atomicAdd(&hist[dv[j] >> 10], 1);
    }
    __syncthreads();
    int cnt = hist[t];
    sd[t] = cnt;
    __syncthreads();
    #pragma unroll
    for (int off = 1; off < 256; off <<= 1) {
        int add = (t >= off) ? sd[t - off] : 0;
        __syncthreads();
        sd[t] += add;
        __syncthreads();
    }
    hofs[t] = sd[t] - cnt;
    hcur[t] = sd[t] - cnt;
    gpos[t] = atomicAdd(&gcur[t], cnt);
    __syncthreads();
    #pragma unroll
    for (int j = 0; j < 16; j++) {
        int e = base + j * 256 + t;
        int d = dv[j];
        int s = ei[e];
        unsigned wq = (unsigned)__float2uint_rn(ew[e] * 16383.f);
        unsigned payload = ((unsigned)s << 14) | wq;
        int p = atomicAdd(&hcur[d >> 10], 1);
        stage[p] = make_uint2((unsigned)d, payload);
    }
    __syncthreads();
    #pragma unroll
    for (int j = 0; j < 16; j++) {
        int k = j * 256 + t;
        uint2 en = stage[k];
        int b = (int)(en.x >> 10);
        bb[gpos[b] + (k - hofs[b])] = en;
    }
}

// ---------- per-bucket count + degree + local rowptr (LDS only, deterministic) ----------
__global__ __launch_bounds__(1024) void count_bucket(const uint2* __restrict__ bb,
                                                     const int* __restrict__ gcur,
                                                     int* __restrict__ rowptr,
                                                     int* __restrict__ btot,
                                                     float* __restrict__ rsqd,
                                                     float* __restrict__ invdeg) {
    __shared__ int cnt[1024];
    __shared__ int wsi[1024];
    __shared__ int sd[1024];
    int b = blockIdx.x, t = threadIdx.x;
    cnt[t] = 0;
    wsi[t] = 0;
    __syncthreads();
    int e0 = b * SLOT, e1 = gcur[b];
    for (int k = e0 + t; k < e1; k += 1024) {
        uint2 en = bb[k];
        int dl = (int)(en.x & 1023u);
        atomicAdd(&cnt[dl], 1);
        atomicAdd(&wsi[dl], (int)(en.y & 16383u));
    }
    __syncthreads();
    int node = (b << 10) + t;
    float deg = 1.f + (float)wsi[t] * (1.f / 16383.f);
    rsqd[node] = rsqrtf(deg);
    invdeg[node] = 1.f / deg;
    int v = cnt[t];
    sd[t] = v;
    __syncthreads();
    #pragma unroll
    for (int off = 1; off < 1024; off <<= 1) {
        int add = (t >= off) ? sd[t - off] : 0;
        __syncthreads();
        sd[t] += add;
        __syncthreads();
    }
    rowptr[node] = sd[t] - v;
    if (t == 1023) btot[b] = sd[1023];
}

__global__ void scan256(const int* __restrict__ btot, int* __restrict__ bbase) {
    __shared__ int sd[256];
    int t = threadIdx.x;
    int v = btot[t];
    sd[t] = v;
    __syncthreads();
    #pragma unroll
    for (int off = 1; off < 256; off <<= 1) {
        int add = (t >= off) ? sd[t - off] : 0;
        __syncthreads();
        sd[t] += add;
        __syncthreads();
    }
    bbase[t] = sd[t] - v;
}

__global__ void finalize_rowptr(int* __restrict__ rowptr, const int* __restrict__ bbase) {
    int i = blockIdx.x * 256 + threadIdx.x;
    rowptr[i] += bbase[i >> 10];
    if (i == 0) rowptr[NN] = EE;
}

// ---------- pass B: per-bucket fine scatter, LDS cursors; applies rsqd[src] ----------
__global__ __launch_bounds__(1024) void binB(const int* __restrict__ rowptr,
                                             const int* __restrict__ gcur,
                                             const uint2* __restrict__ bb,
                                             const float* __restrict__ rsqd,
                                             unsigned* __restrict__ evw) {
    __shared__ int lcur[1024];
    int b = blockIdx.x, t = threadIdx.x;
    lcur[t] = rowptr[(b << 10) + t];
    __syncthreads();
    int e0 = b * SLOT, e1 = gcur[b];
    for (int k = e0 + t; k < e1; k += 1024) {
        uint2 en = bb[k];
        int dl = (int)(en.x & 1023u);
        unsigned s = en.y >> 14;
        float wt = (float)(en.y & 16383u) * (1.f / 16383.f) * rsqd[s];
        int pos = atomicAdd(&lcur[dl], 1);
        evw[pos] = (s << 14) | (unsigned)__float2uint_rn(wt * 16383.f);
    }
}

// ---------- layer-0 scores fused with f32->f16 table conversion ----------
__global__ void scores0_f16(const float* __restrict__ x, const float* __restrict__ pn0,
                            float* __restrict__ scores, unsigned short* __restrict__ xh) {
    __shared__ float p[32];
    if (threadIdx.x < 32) p[threadIdx.x] = pn0[threadIdx.x];
    __syncthreads();
    int n = blockIdx.x * 256 + threadIdx.x;
    const float4* xr = (const float4*)(x + (size_t)n * 32);
    float s = 0.f;
    unsigned wv[16];
    #pragma unroll
    for (int j = 0; j < 8; j++) {
        float4 v = xr[j];
        s += v.x * p[j * 4] + v.y * p[j * 4 + 1] + v.z * p[j * 4 + 2] + v.w * p[j * 4 + 3];
        wv[2 * j]     = (unsigned)f2h(v.x) | ((unsigned)f2h(v.y) << 16);
        wv[2 * j + 1] = (unsigned)f2h(v.z) | ((unsigned)f2h(v.w) << 16);
    }
    uint4* xo = (uint4*)(xh + (size_t)n * 32);
    xo[0] = make_uint4(wv[0], wv[1], wv[2], wv[3]);
    xo[1] = make_uint4(wv[4], wv[5], wv[6], wv[7]);
    xo[2] = make_uint4(wv[8], wv[9], wv[10], wv[11]);
    xo[3] = make_uint4(wv[12], wv[13], wv[14], wv[15]);
    scores[n] = s;
}

// ---------- two-stage per-graph top-7 ----------
__global__ void topk1(const float* __restrict__ scores, float2* __restrict__ cand) {
    int g = blockIdx.x >> 4, c = blockIdx.x & 15;
    int t = threadIdx.x;
    float lv[KK];
    int li[KK];
    #pragma unroll
    for (int j = 0; j < KK; j++) { lv[j] = -INFINITY; li[j] = 0; }
    const float* sg = scores + (size_t)g * NPER + c * 1024;
    #pragma unroll
    for (int it = 0; it < 4; ++it) {
        int idx = it * 256 + t;
        float v = sg[idx];
        if (v > lv[KK - 1]) {
            int j = KK - 1;
            while (j > 0 && lv[j - 1] < v) { lv[j] = lv[j - 1]; li[j] = li[j - 1]; j--; }
            lv[j] = v; li[j] = idx;
        }
    }
    __shared__ float sval[256];
    __shared__ int sidx[256];
    __shared__ int swin;
    int cons = 0;
    for (int r = 0; r < KK; r++) {
        sval[t] = (cons < KK) ? lv[cons] : -INFINITY;
        sidx[t] = t;
        __syncthreads();
        for (int s = 128; s > 0; s >>= 1) {
            if (t < s) {
                if (sval[t + s] > sval[t]) { sval[t] = sval[t + s]; sidx[t] = sidx[t + s]; }
            }
            __syncthreads();
        }
        if (t == 0) swin = sidx[0];
        __syncthreads();
        if (t == swin) {
            cand[blockIdx.x * KK + r] =
                make_float2(lv[cons], __int_as_float(g * NPER + c * 1024 + li[cons]));
            cons++;
        }
        __syncthreads();
    }
}

__global__ void topk2(const float2* __restrict__ cand, float* __restrict__ topv,
                      int* __restrict__ topi) {
    int g = blockIdx.x, t = threadIdx.x; // 128 threads
    float v = -INFINITY;
    int id = 0;
    if (t < 16 * KK) {
        float2 cv = cand[g * 16 * KK + t];
        v = cv.x;
        id = __float_as_int(cv.y);
    }
    __shared__ float sval[128];
    __shared__ int sidx[128];
    __shared__ int swin;
    for (int r = 0; r < KK; r++) {
        sval[t] = v;
        sidx[t] = t;
        __syncthreads();
        for (int s = 64; s > 0; s >>= 1) {
            if (t < s) {
                if (sval[t + s] > sval[t]) { sval[t] = sval[t + s]; sidx[t] = sidx[t + s]; }
            }
            __syncthreads();
        }
        if (t == 0) swin = sidx[0];
        __syncthreads();
        if (t == swin) {
            topv[g * KK + r] = v;
            topi[g * KK + r] = id;
            v = -INFINITY;
        }
        __syncthreads();
    }
}

// ---------- Z = mean_k tanh(s)*h[idx] ----------
__global__ void z_kernel(const float* __restrict__ h, int din, const float* __restrict__ topv,
                         const int* __restrict__ topi, float* __restrict__ Z) {
    int b = blockIdx.x;
    int d = threadIdx.x;
    if (d >= din) return;
    float acc = 0.f;
    for (int j = 0; j < KK; j++) {
        acc += tanhf(topv[b * KK + j]) * h[(size_t)topi[b * KK + j] * din + d];
    }
    Z[b * din + d] = acc * (1.f / 7.f);
}

__global__ void z_kernel_h(const unsigned short* __restrict__ h, int din,
                           const float* __restrict__ topv, const int* __restrict__ topi,
                           float* __restrict__ Z) {
    int b = blockIdx.x;
    int d = threadIdx.x;
    if (d >= din) return;
    float acc = 0.f;
    for (int j = 0; j < KK; j++) {
        acc += tanhf(topv[b * KK + j]) * h2f(h[(size_t)topi[b * KK + j] * din + d]);
    }
    Z[b * din + d] = acc * (1.f / 7.f);
}

// ---------- GRU: per-slice partial matvec, 4 rows per 16-lane group ----------
__global__ void gru_matvec(const float* __restrict__ Whh, const float* __restrict__ gh,
                           float* __restrict__ ghl, int P) {
    int t = threadIdx.x;
    int g = t >> 4, l16 = t & 15;
    int row0 = blockIdx.x * 64 + g * 4;
    int k0 = blockIdx.y * 512;
    float acc[4][16];
    #pragma unroll
    for (int r = 0; r < 4; r++)
        #pragma unroll
        for (int b = 0; b < 16; b++) acc[r][b] = 0.f;
    const float* wr = Whh + (size_t)row0 * P + k0 + l16 * 4;
    const float* gr = gh + k0 + l16 * 4;
    for (int kk = 0; kk < 8; ++kk) {
        float4 a0 = *(const float4*)(wr + kk * 64);
        float4 a1 = *(const float4*)(wr + (size_t)P + kk * 64);
        float4 a2 = *(const float4*)(wr + (size_t)2 * P + kk * 64);
        float4 a3 = *(const float4*)(wr + (size_t)3 * P + kk * 64);
        #pragma unroll
        for (int b = 0; b < 16; b++) {
            float4 gv = *(const float4*)(gr + (size_t)b * P + kk * 64);
            acc[0][b] += a0.x * gv.x + a0.y * gv.y + a0.z * gv.z + a0.w * gv.w;
            acc[1][b] += a1.x * gv.x + a1.y * gv.y + a1.z * gv.z + a1.w * gv.w;
            acc[2][b] += a2.x * gv.x + a2.y * gv.y + a2.z * gv.z + a2.w * gv.w;
            acc[3][b] += a3.x * gv.x + a3.y * gv.y + a3.z * gv.z + a3.w * gv.w;
        }
    }
    size_t sstr = (size_t)gridDim.x * 1024; // rows*16
    #pragma unroll
    for (int r = 0; r < 4; r++) {
        #pragma unroll
        for (int b = 0; b < 16; b++) {
            float v = acc[r][b];
            v += __shfl_xor(v, 1); v += __shfl_xor(v, 2);
            v += __shfl_xor(v, 4); v += __shfl_xor(v, 8);
            if (l16 == b) ghl[(size_t)blockIdx.y * sstr + (size_t)(row0 + r) * 16 + b] = v;
        }
    }
}

// ---------- GRU gates, batch-split: block (pb, b) computes gv[b][p] ----------
__global__ __launch_bounds__(256) void gate_kernel(
    const float* __restrict__ Wih, const float* __restrict__ bih,
    const float* __restrict__ bhh, const float* __restrict__ gh,
    const float* __restrict__ ghl, const float* __restrict__ Zg,
    float* __restrict__ gvt, int P, int din, int NS) {
    __shared__ float Zs[64];
    int t = threadIdx.x;
    int b = blockIdx.y;
    if (t < din) Zs[t] = Zg[b * din + t];
    __syncthreads();
    int p = blockIdx.x * 256 + t;
    float ir = bih[p], iz = bih[P + p], inn = bih[2 * P + p];
    const float* w_r = Wih + (size_t)p * din;
    const float* w_z = Wih + (size_t)(P + p) * din;
    const float* w_n = Wih + (size_t)(2 * P + p) * din;
    for (int d = 0; d < din; d += 4) {
        float4 zr = *(const float4*)(Zs + d);
        float4 a = *(const float4*)(w_r + d);
        float4 bq = *(const float4*)(w_z + d);
        float4 c = *(const float4*)(w_n + d);
        ir += a.x * zr.x + a.y * zr.y + a.z * zr.z + a.w * zr.w;
        iz += bq.x * zr.x + bq.y * zr.y + bq.z * zr.z + bq.w * zr.w;
        inn += c.x * zr.x + c.y * zr.y + c.z * zr.z + c.w * zr.w;
    }
    float hr = bhh[p], hz = bhh[P + p], hn = bhh[2 * P + p];
    size_t sstr = (size_t)48 * P;
    for (int s2 = 0; s2 < NS; s2++) {
        const float* g2 = ghl + (size_t)s2 * sstr;
        hr += g2[(size_t)p * 16 + b];
        hz += g2[(size_t)(P + p) * 16 + b];
        hn += g2[(size_t)(2 * P + p) * 16 + b];
    }
    float r = 1.f / (1.f + expf(-(ir + hr)));
    float z = 1.f / (1.f + expf(-(iz + hz)));
    float n = tanhf(inn + r * hn);
    float hprev = gh[(size_t)b * P + p];
    gvt[(size_t)b * P + p] = (1.f - z) * n + z * hprev;
}

// Wev[p] = mean over 16 batches
__global__ void gate_reduce(const float* __restrict__ gvt, float* __restrict__ Wev, int P) {
    int p = blockIdx.x * 256 + threadIdx.x;
    float s = 0.f;
    #pragma unroll
    for (int b = 0; b < 16; b++) s += gvt[(size_t)b * P + p];
    Wev[p] = s * (1.f / 16.f);
}

// ---------- edge aggregation: 4 dims/lane (uint2 gather), f16 output ----------
template<int DIN, int LSHL>
__global__ void agg_kernel(const unsigned short* __restrict__ hin,
                           const int* __restrict__ rowptr, const unsigned* __restrict__ evw,
                           const float* __restrict__ rsqd, const float* __restrict__ invdeg,
                           unsigned short* __restrict__ aggh, float* __restrict__ cc) {
    int t = threadIdx.x;
    int lane = t & ((1 << LSHL) - 1);
    int i = blockIdx.x * (256 >> LSHL) + (t >> LSHL);
    int e0 = rowptr[i], e1 = rowptr[i + 1];
    float a0 = 0.f, a1 = 0.f, a2 = 0.f, a3 = 0.f;
    int csi = 0;
    for (int e = e0; e < e1; e += 8) {
        unsigned ev[8];
        #pragma unroll
        for (int j = 0; j < 8; j++) {
            ev[j] = (e + j < e1) ? evw[e + j] : ((unsigned)i << 14);
        }
        uint2 hv[8];
        #pragma unroll
        for (int j = 0; j < 8; j++) {
            hv[j] = *(const uint2*)(hin + (size_t)(ev[j] >> 14) * DIN + 4 * lane);
        }
        #pragma unroll
        for (int j = 0; j < 8; j++) {
            int wq = (int)(ev[j] & 16383u);
            csi += wq;
            float nw = (float)wq;
            a0 += nw * h2f((unsigned short)(hv[j].x & 0xffffu));
            a1 += nw * h2f((unsigned short)(hv[j].x >> 16));
            a2 += nw * h2f((unsigned short)(hv[j].y & 0xffffu));
            a3 += nw * h2f((unsigned short)(hv[j].y >> 16));
        }
    }
    float rsi = rsqd[i] * (1.f / 16383.f);
    float idg = invdeg[i];
    uint2 hs = *(const uint2*)(hin + (size_t)i * DIN + 4 * lane);
    float r0 = a0 * rsi + h2f((unsigned short)(hs.x & 0xffffu)) * idg;
    float r1 = a1 * rsi + h2f((unsigned short)(hs.x >> 16)) * idg;
    float r2 = a2 * rsi + h2f((unsigned short)(hs.y & 0xffffu)) * idg;
    float r3 = a3 * rsi + h2f((unsigned short)(hs.y >> 16)) * idg;
    uint2 ro;
    ro.x = (unsigned)f2h(r0) | ((unsigned)f2h(r1) << 16);
    ro.y = (unsigned)f2h(r2) | ((unsigned)f2h(r3) << 16);
    *(uint2*)(aggh + (size_t)i * DIN + 4 * lane) = ro;
    #pragma unroll
    for (int o = (1 << LSHL) >> 1; o > 0; o >>= 1) csi += __shfl_xor(csi, o);
    if (lane == 0) cc[i] = (float)csi * rsi + idg;
}

// ---------- post kernels: 4 waves/block, LDS-staged A tiles (f16 agg input) ----------
__global__ __launch_bounds__(256) void post0_kernel(
    const unsigned short* __restrict__ aggh, const float* __restrict__ cc,
    const float* __restrict__ Wev, const float* __restrict__ gcnb,
    const float* __restrict__ lng, const float* __restrict__ lnb,
    const float* __restrict__ pn1, unsigned short* __restrict__ h1h,
    float* __restrict__ scores) {
    __shared__ float stage[4][512];
    __shared__ float tile[4][64 * TPAD];
    const int wv = threadIdx.x >> 6;
    const int lane = threadIdx.x & 63;
    const int tb = blockIdx.x * 256 + wv * 64;
    const int j = lane & 15, q = lane >> 4;
    float gL = gcnb[lane];
    float lgv[16], lbv[16], pnv[16];
    #pragma unroll
    for (int r = 0; r < 16; r++) {
        lgv[r] = lng[q * 16 + r];
        lbv[r] = lnb[q * 16 + r];
        pnv[r] = pn1[q * 16 + r];
    }
    float* st = stage[wv];
    float* trow = tile[wv] + lane * TPAD;
    auto do_chunk = [&](int C) {
        __syncthreads();
        {
            const uint2* src = (const uint2*)(aggh + (size_t)(tb + C * 16) * 32);
            #pragma unroll
            for (int it = 0; it < 2; ++it) {
                uint2 hp = src[it * 64 + lane];
                float4 f;
                f.x = h2f((unsigned short)(hp.x & 0xffffu));
                f.y = h2f((unsigned short)(hp.x >> 16));
                f.z = h2f((unsigned short)(hp.y & 0xffffu));
                f.w = h2f((unsigned short)(hp.y >> 16));
                *(float4*)(st + (it * 64 + lane) * 4) = f;
            }
        }
        __syncthreads();
        float v[16];
        #pragma unroll
        for (int k = 0; k < 16; k++) v[k] = 0.f;
        for (int db = 0; db < 8; ++db) {
            float wc0 = Wev[(db * 4 + 0) * 64 + lane];
            float wc1 = Wev[(db * 4 + 1) * 64 + lane];
            float wc2 = Wev[(db * 4 + 2) * 64 + lane];
            float wc3 = Wev[(db * 4 + 3) * 64 + lane];
            #pragma unroll
            for (int k = 0; k < 16; k++) {
                float4 a = *(const float4*)(st + k * 32 + db * 4);
                v[k] += a.x * wc0 + a.y * wc1 + a.z * wc2 + a.w * wc3;
            }
        }
        __syncthreads();
        #pragma unroll
        for (int k = 0; k < 16; k++) trow[k] = v[k] + gL * cc[tb + C * 16 + k];
        __syncthreads();
        float av[16];
        #pragma unroll
        for (int r = 0; r < 16; r++) av[r] = tile[wv][(q * 16 + r) * TPAD + j];
        float s1 = 0.f, s2 = 0.f;
        #pragma unroll
        for (int r = 0; r < 16; r++) { s1 += av[r]; s2 += av[r] * av[r]; }
        s1 += __shfl_xor(s1, 16); s1 += __shfl_xor(s1, 32);
        s2 += __shfl_xor(s2, 16); s2 += __shfl_xor(s2, 32);
        float mu = s1 * (1.f / 64.f);
        float rstd = rsqrtf(s2 * (1.f / 64.f) - mu * mu + 1e-5f);
        float hv[16];
        float sc = 0.f;
        #pragma unroll
        for (int r = 0; r < 16; r++) {
            hv[r] = fmaxf((av[r] - mu) * rstd * lgv[r] + lbv[r], 0.f);
            sc += hv[r] * pnv[r];
        }
        int node = tb + C * 16 + j;
        uint4 o0, o1;
        o0.x = (unsigned)f2h(hv[0])  | ((unsigned)f2h(hv[1])  << 16);
        o0.y = (unsigned)f2h(hv[2])  | ((unsigned)f2h(hv[3])  << 16);
        o0.z = (unsigned)f2h(hv[4])  | ((unsigned)f2h(hv[5])  << 16);
        o0.w = (unsigned)f2h(hv[6])  | ((unsigned)f2h(hv[7])  << 16);
        o1.x = (unsigned)f2h(hv[8])  | ((unsigned)f2h(hv[9])  << 16);
        o1.y = (unsigned)f2h(hv[10]) | ((unsigned)f2h(hv[11]) << 16);
        o1.z = (unsigned)f2h(hv[12]) | ((unsigned)f2h(hv[13]) << 16);
        o1.w = (unsigned)f2h(hv[14]) | ((unsigned)f2h(hv[15]) << 16);
        *(uint4*)(h1h + (size_t)node * 64 + q * 16) = o0;
        *(uint4*)(h1h + (size_t)node * 64 + q * 16 + 8) = o1;
        sc += __shfl_xor(sc, 16); sc += __shfl_xor(sc, 32);
        if (q == 0) scores[node] = sc;
    };
    do_chunk(0); do_chunk(1); do_chunk(2); do_chunk(3);
}

__global__ __launch_bounds__(256) void post1_kernel(
    const unsigned short* __restrict__ aggh, const float* __restrict__ cc,
    const float* __restrict__ Wev, const float* __restrict__ gcnb,
    const float* __restrict__ lng, const float* __restrict__ lnb,
    const float* __restrict__ Wp, const float* __restrict__ bp,
    float* __restrict__ out) {
    __shared__ float stage[4][1024];
    __shared__ float tile[4][64 * TPAD];
    const int wv = threadIdx.x >> 6;
    const int lane = threadIdx.x & 63;
    const int tb = blockIdx.x * 256 + wv * 64;
    const int j = lane & 15, q = lane >> 4;
    float gL = gcnb[lane];
    float lgv[16], lbv[16];
    #pragma unroll
    for (int r = 0; r < 16; r++) {
        lgv[r] = lng[q * 16 + r];
        lbv[r] = lnb[q * 16 + r];
    }
    float bpv[10];
    #pragma unroll
    for (int t2 = 0; t2 < 10; t2++) bpv[t2] = bp[t2];
    float* st = stage[wv];
    float* trow = tile[wv] + lane * TPAD;
    auto do_chunk = [&](int C) {
        __syncthreads();
        {
            const uint2* src = (const uint2*)(aggh + (size_t)(tb + C * 16) * 64);
            #pragma unroll
            for (int it = 0; it < 4; ++it) {
                uint2 hp = src[it * 64 + lane];
                float4 f;
                f.x = h2f((unsigned short)(hp.x & 0xffffu));
                f.y = h2f((unsigned short)(hp.x >> 16));
                f.z = h2f((unsigned short)(hp.y & 0xffffu));
                f.w = h2f((unsigned short)(hp.y >> 16));
                *(float4*)(st + (it * 64 + lane) * 4) = f;
            }
        }
        __syncthreads();
        float v[16];
        #pragma unroll
        for (int k = 0; k < 16; k++) v[k] = 0.f;
        for (int db = 0; db < 16; ++db) {
            float wc0 = Wev[(db * 4 + 0) * 64 + lane];
            float wc1 = Wev[(db * 4 + 1) * 64 + lane];
            float wc2 = Wev[(db * 4 + 2) * 64 + lane];
            float wc3 = Wev[(db * 4 + 3) * 64 + lane];
            #pragma unroll
            for (int k = 0; k < 16; k++) {
                float4 a = *(const float4*)(st + k * 64 + db * 4);
                v[k] += a.x * wc0 + a.y * wc1 + a.z * wc2 + a.w * wc3;
            }
        }
        __syncthreads();
        #pragma unroll
        for (int k = 0; k < 16; k++) trow[k] = v[k] + gL * cc[tb + C * 16 + k];
        __syncthreads();
        float av[16];
        #pragma unroll
        for (int r = 0; r < 16; r++) av[r] = tile[wv][(q * 16 + r) * TPAD + j];
        float s1 = 0.f, s2 = 0.f;
        #pragma unroll
        for (int r = 0; r < 16; r++) { s1 += av[r]; s2 += av[r] * av[r]; }
        s1 += __shfl_xor(s1, 16); s1 += __shfl_xor(s1, 32);
        s2 += __shfl_xor(s2, 16); s2 += __shfl_xor(s2, 32);
        float mu = s1 * (1.f / 64.f);
        float rstd = rsqrtf(s2 * (1.f / 64.f) - mu * mu + 1e-5f);
        float hv[16];
        #pragma unroll
        for (int r = 0; r < 16; r++)
            hv[r] = fmaxf((av[r] - mu) * rstd * lgv[r] + lbv[r], 0.f);
        float oa[10];
        #pragma unroll
        for (int t2 = 0; t2 < 10; t2++) oa[t2] = 0.f;
        #pragma unroll
        for (int r = 0; r < 16; r++) {
            const float* wpb = Wp + (size_t)(q * 16 + r) * 2;
            float2 w0 = *(const float2*)(wpb);
            float2 w1 = *(const float2*)(wpb + 128);
            float2 w2 = *(const float2*)(wpb + 256);
            float2 w3 = *(const float2*)(wpb + 384);
            float2 w4 = *(const float2*)(wpb + 512);
            oa[0] += hv[r] * w0.x; oa[1] += hv[r] * w0.y;
            oa[2] += hv[r] * w1.x; oa[3] += hv[r] * w1.y;
            oa[4] += hv[r] * w2.x; oa[5] += hv[r] * w2.y;
            oa[6] += hv[r] * w3.x; oa[7] += hv[r] * w3.y;
            oa[8] += hv[r] * w4.x; oa[9] += hv[r] * w4.y;
        }
        #pragma unroll
        for (int t2 = 0; t2 < 10; t2++) {
            oa[t2] += __shfl_xor(oa[t2], 16);
            oa[t2] += __shfl_xor(oa[t2], 32);
        }
        if (q == 0) {
            int node = tb + C * 16 + j;
            #pragma unroll
            for (int t2 = 0; t2 < 10; t2++) out[(size_t)node * 10 + t2] = oa[t2] + bpv[t2];
        }
    };
    do_chunk(0); do_chunk(1); do_chunk(2); do_chunk(3);
}

extern "C" void kernel_launch(void* const* d_in, const int* in_sizes, int n_in,
                              void* d_out, int out_size, void* d_ws, size_t ws_size,
                              hipStream_t stream) {
    const float* x     = (const float*)d_in[0];
    const int*   ei    = (const int*)d_in[1];
    const float* ew    = (const float*)d_in[2];
    const float* p0    = (const float*)d_in[5];
    const float* p1    = (const float*)d_in[6];
    const float* Wih0  = (const float*)d_in[7];
    const float* Whh0  = (const float*)d_in[8];
    const float* bih0  = (const float*)d_in[9];
    const float* bhh0  = (const float*)d_in[10];
    const float* Wih1  = (const float*)d_in[11];
    const float* Whh1  = (const float*)d_in[12];
    const float* bih1  = (const float*)d_in[13];
    const float* bhh1  = (const float*)d_in[14];
    const float* gruh0 = (const float*)d_in[15];
    const float* gruh1 = (const float*)d_in[16];
    const float* gcnb0 = (const float*)d_in[17];
    const float* gcnb1 = (const float*)d_in[18];
    const float* lng0  = (const float*)d_in[19];
    const float* lnb0  = (const float*)d_in[20];
    const float* lng1  = (const float*)d_in[21];
    const float* lnb1  = (const float*)d_in[22];
    const float* Wp    = (const float*)d_in[23];
    const float* bp    = (const float*)d_in[24];
    float* out = (float*)d_out;

    // workspace carve
    char* w = (char*)d_ws;
    size_t off = 0;
    auto alloc = [&](size_t bytes) -> void* {
        void* p = w + off;
        off += (bytes + 255) & ~(size_t)255;
        return p;
    };
    int*      rowptr = (int*)alloc((NN + 1) * sizeof(int));
    unsigned* evw    = (unsigned*)alloc((size_t)EE * sizeof(unsigned));
    float*    rsqd   = (float*)alloc(NN * sizeof(float));
    float*    invdeg = (float*)alloc(NN * sizeof(float));
    float*    scores = (float*)alloc(NN * sizeof(float));
    float*    topv   = (float*)alloc(NG * KK * sizeof(float));
    int*      topi   = (int*)alloc(NG * KK * sizeof(int));
    float2*   cand   = (float2*)alloc(NG * 16 * KK * sizeof(float2));
    float*    Z      = (float*)alloc(16 * 64 * sizeof(float));
    float*    ghl    = (float*)alloc((size_t)8 * 196608 * sizeof(float));
    float*    gvt    = (float*)alloc((size_t)16 * 4096 * sizeof(float));
    float*    Wev    = (float*)alloc(4096 * sizeof(float));
    float*    cc     = (float*)alloc(NN * sizeof(float));
    float*    agg    = (float*)alloc((size_t)NN * 64 * sizeof(float));
    unsigned short* xh  = (unsigned short*)alloc((size_t)NN * 32 * sizeof(unsigned short));
    unsigned short* h1h = (unsigned short*)alloc((size_t)NN * 64 * sizeof(unsigned short));
    float*    pn     = (float*)alloc(96 * sizeof(float));
    int*      gcur   = (int*)alloc(256 * sizeof(int));
    int*      btot   = (int*)alloc(256 * sizeof(int));
    int*      bbase  = (int*)alloc(256 * sizeof(int));

    // bb (256*SLOT*8B = 37.75MB) aliases into agg (67MB); aggh (f16) also in agg.
    uint2* bb = (uint2*)agg;
    unsigned short* aggh = (unsigned short*)agg;

    // --- CSR build: fixed-slot radix partition -> per-bucket count -> scatter ---
    init_gcur<<<1, 256, 0, stream>>>(gcur);
    prep_p<<<1, 64, 0, stream>>>(p0, p1, pn);
    binA<<<EE / 4096, 256, 0, stream>>>(ei, ew, gcur, bb);
    count_bucket<<<256, 1024, 0, stream>>>(bb, gcur, rowptr, btot, rsqd, invdeg);
    scan256<<<1, 256, 0, stream>>>(btot, bbase);
    finalize_rowptr<<<NN / 256, 256, 0, stream>>>(rowptr, bbase);
    binB<<<256, 1024, 0, stream>>>(rowptr, gcur, bb, rsqd, evw);

    // --- layer 0 ---
    scores0_f16<<<NN / 256, 256, 0, stream>>>(x, pn, scores, xh);
    topk1<<<NG * 16, 256, 0, stream>>>(scores, cand);
    topk2<<<NG, 128, 0, stream>>>(cand, topv, topi);
    z_kernel<<<NG, 32, 0, stream>>>(x, 32, topv, topi, Z);
    gru_matvec<<<dim3(6144 / 64, 4), 256, 0, stream>>>(Whh0, gruh0, ghl, 2048);
    gate_kernel<<<dim3(2048 / 256, 16), 256, 0, stream>>>(Wih0, bih0, bhh0, gruh0, ghl, Z, gvt, 2048, 32, 4);
    gate_reduce<<<2048 / 256, 256, 0, stream>>>(gvt, Wev, 2048);
    agg_kernel<32, 3><<<NN / 32, 256, 0, stream>>>(xh, rowptr, evw, rsqd, invdeg, aggh, cc);
    post0_kernel<<<NN / 256, 256, 0, stream>>>(aggh, cc, Wev, gcnb0, lng0, lnb0, pn + 32, h1h, scores);

    // --- layer 1 ---
    topk1<<<NG * 16, 256, 0, stream>>>(scores, cand);
    topk2<<<NG, 128, 0, stream>>>(cand, topv, topi);
    z_kernel_h<<<NG, 64, 0, stream>>>(h1h, 64, topv, topi, Z);
    gru_matvec<<<dim3(12288 / 64, 8), 256, 0, stream>>>(Whh1, gruh1, ghl, 4096);
    gate_kernel<<<dim3(4096 / 256, 16), 256, 0, stream>>>(Wih1, bih1, bhh1, gruh1, ghl, Z, gvt, 4096, 64, 8);
    gate_reduce<<<4096 / 256, 256, 0, stream>>>(gvt, Wev, 4096);
    agg_kernel<64, 4><<<NN / 16, 256, 0, stream>>>(h1h, rowptr, evw, rsqd, invdeg, aggh, cc);
    post1_kernel<<<NN / 256, 256, 0, stream>>>(aggh, cc, Wev, gcnb1, lng1, lnb1, Wp, bp, out);
}